// Round 6
// baseline (168.498 us; speedup 1.0000x reference)
//
#include <hip/hip_runtime.h>
#include <hip/hip_bf16.h>
#include <math.h>

// MultiSimilarityLoss B=8192 D=128: sim = F·F^T via bf16 MFMA (16x16x32).
// R6: software-pipelined j-stream (prefetch next jfr between MFMA and the
// trailing epilogue half), paired MFMA batches, exp2-folded constants,
// ms1 ONE_EPS compare dropped (validity via ps>0 && ns>0 in fin).
// Roles: streamed j = A operand, persistent i = B operand -> D col = i.

#define B_N    8192
#define DDIM   128
#define JSPLIT 32
#define JRANGE (B_N / JSPLIT)    // 256 j per block
#define JT     16                // j rows per iteration
#define NJT    (JRANGE / JT)     // 16 iterations
#define NG     4                 // 16-i groups per wave (64 i per wave)

typedef __attribute__((ext_vector_type(8))) short bf16x8;  // 8 bf16 = 4 VGPRs
typedef __attribute__((ext_vector_type(4))) float f32x4;

static constexpr float ONE_EPS  = 1.0f - 1e-5f;
static constexpr float F_MARGIN = 0.1f;
// exp2-folded: exp(-2(s-.5)) = 2^(-2*log2e*s + log2e) ; exp(40(s-.5)) = 2^(40*log2e*s - 20*log2e)
static constexpr float KP2A = -2.8853900817779268f, KP2B =  1.4426950408889634f;
static constexpr float KN2A = 57.7078016355585400f, KN2B = -28.8539008177792680f;

// ---------------------------------------------------------------- cast fp32 -> bf16 (RNE)
__global__ __launch_bounds__(256)
void ms_cast(const float* __restrict__ f, ushort* __restrict__ fb)
{
    int i = (blockIdx.x * 256 + threadIdx.x) * 4;
    float4 v = *(const float4*)(f + i);
    ushort4 o;
    uint u;
    u = __float_as_uint(v.x); o.x = (ushort)((u + 0x7fffu + ((u >> 16) & 1u)) >> 16);
    u = __float_as_uint(v.y); o.y = (ushort)((u + 0x7fffu + ((u >> 16) & 1u)) >> 16);
    u = __float_as_uint(v.z); o.z = (ushort)((u + 0x7fffu + ((u >> 16) & 1u)) >> 16);
    u = __float_as_uint(v.w); o.w = (ushort)((u + 0x7fffu + ((u >> 16) & 1u)) >> 16);
    *(ushort4*)(fb + i) = o;
}

// ---------------------------------------------------------------- stage 1: min_pos / max_neg
__global__ __launch_bounds__(256, 4)
void ms1(const ushort* __restrict__ fb, const int* __restrict__ labels,
         float* __restrict__ minp_part, float* __restrict__ maxn_part)
{
    const int tid  = threadIdx.x;
    const int w    = tid >> 6, lane = tid & 63;
    const int q    = lane >> 4, c = lane & 15;
    const int i0   = blockIdx.x * 256;
    const int j0   = blockIdx.y * JRANGE;
    const int iw0  = i0 + w * 64;

    bf16x8 ifr[NG][4];
    int    li[NG];
    #pragma unroll
    for (int g = 0; g < NG; ++g) {
        int row = iw0 + g * 16 + c;
        #pragma unroll
        for (int ks = 0; ks < 4; ++ks)
            ifr[g][ks] = *(const bf16x8*)(fb + row * DDIM + ks * 32 + q * 8);
        li[g] = labels[row];
    }

    float vmin[NG], vmax[NG];
    #pragma unroll
    for (int g = 0; g < NG; ++g) { vmin[g] = INFINITY; vmax[g] = -INFINITY; }

    const ushort* jptr = fb + (size_t)(j0 + c) * DDIM + q * 8;
    const int*    lptr = labels + j0 + q * 4;

    bf16x8 jfr[4];
    #pragma unroll
    for (int ks = 0; ks < 4; ++ks) jfr[ks] = *(const bf16x8*)(jptr + ks * 32);
    int4 lj = *(const int4*)lptr;

    #pragma unroll 1
    for (int jt = 0; jt < NJT; ++jt) {
        const int nj = (jt + 1) & (NJT - 1);          // wrap: last prefetch unused
        const ushort* np = jptr + (size_t)nj * JT * DDIM;
        const int*    nl = lptr + nj * JT;

        f32x4 a0 = {0.f,0.f,0.f,0.f}, a1 = {0.f,0.f,0.f,0.f};
        #pragma unroll
        for (int ks = 0; ks < 4; ++ks) a0 = __builtin_amdgcn_mfma_f32_16x16x32_bf16(jfr[ks], ifr[0][ks], a0, 0, 0, 0);
        #pragma unroll
        for (int ks = 0; ks < 4; ++ks) a1 = __builtin_amdgcn_mfma_f32_16x16x32_bf16(jfr[ks], ifr[1][ks], a1, 0, 0, 0);
        const int4 ljc = lj;

        #pragma unroll
        for (int r = 0; r < 4; ++r) {
            int ljr = (r == 0) ? ljc.x : (r == 1) ? ljc.y : (r == 2) ? ljc.z : ljc.w;
            float s0 = a0[r]; bool m0 = (li[0] == ljr);
            vmin[0] = fminf(vmin[0], m0 ? s0 : INFINITY);
            vmax[0] = fmaxf(vmax[0], m0 ? -INFINITY : s0);
            float s1 = a1[r]; bool m1 = (li[1] == ljr);
            vmin[1] = fminf(vmin[1], m1 ? s1 : INFINITY);
            vmax[1] = fmaxf(vmax[1], m1 ? -INFINITY : s1);
        }

        f32x4 a2 = {0.f,0.f,0.f,0.f}, a3 = {0.f,0.f,0.f,0.f};
        #pragma unroll
        for (int ks = 0; ks < 4; ++ks) a2 = __builtin_amdgcn_mfma_f32_16x16x32_bf16(jfr[ks], ifr[2][ks], a2, 0, 0, 0);
        #pragma unroll
        for (int ks = 0; ks < 4; ++ks) a3 = __builtin_amdgcn_mfma_f32_16x16x32_bf16(jfr[ks], ifr[3][ks], a3, 0, 0, 0);

        // prefetch next j-tile (jfr dead after the MFMAs above)
        #pragma unroll
        for (int ks = 0; ks < 4; ++ks) jfr[ks] = *(const bf16x8*)(np + ks * 32);
        lj = *(const int4*)nl;

        #pragma unroll
        for (int r = 0; r < 4; ++r) {
            int ljr = (r == 0) ? ljc.x : (r == 1) ? ljc.y : (r == 2) ? ljc.z : ljc.w;
            float s2 = a2[r]; bool m2 = (li[2] == ljr);
            vmin[2] = fminf(vmin[2], m2 ? s2 : INFINITY);
            vmax[2] = fmaxf(vmax[2], m2 ? -INFINITY : s2);
            float s3 = a3[r]; bool m3 = (li[3] == ljr);
            vmin[3] = fminf(vmin[3], m3 ? s3 : INFINITY);
            vmax[3] = fmaxf(vmax[3], m3 ? -INFINITY : s3);
        }
    }

    #pragma unroll
    for (int g = 0; g < NG; ++g) {
        vmin[g] = fminf(vmin[g], __shfl_xor(vmin[g], 16, 64));
        vmin[g] = fminf(vmin[g], __shfl_xor(vmin[g], 32, 64));
        vmax[g] = fmaxf(vmax[g], __shfl_xor(vmax[g], 16, 64));
        vmax[g] = fmaxf(vmax[g], __shfl_xor(vmax[g], 32, 64));
    }
    if (q == 0) {
        #pragma unroll
        for (int g = 0; g < NG; ++g) {
            int row = iw0 + g * 16 + c;
            minp_part[blockIdx.y * B_N + row] = vmin[g];
            maxn_part[blockIdx.y * B_N + row] = vmax[g];
        }
    }
}

// ---------------------------------------------------------------- stage 2: masked exp sums
__global__ __launch_bounds__(256, 4)
void ms2(const ushort* __restrict__ fb, const int* __restrict__ labels,
         const float* __restrict__ minp_part, const float* __restrict__ maxn_part,
         float* __restrict__ psum_part, float* __restrict__ nsum_part)
{
    const int tid  = threadIdx.x;
    const int w    = tid >> 6, lane = tid & 63;
    const int q    = lane >> 4, c = lane & 15;
    const int i0   = blockIdx.x * 256;
    const int j0   = blockIdx.y * JRANGE;
    const int iw0  = i0 + w * 64;

    // fold stage-1 partials -> bounds: pb = min(1-eps, max_neg+margin); nb = min_pos-margin
    __shared__ float spb[256], snb[256];
    {
        int row = i0 + tid;
        float mn = INFINITY, mx = -INFINITY;
        #pragma unroll
        for (int s = 0; s < JSPLIT; ++s) {
            mn = fminf(mn, minp_part[s * B_N + row]);
            mx = fmaxf(mx, maxn_part[s * B_N + row]);
        }
        spb[tid] = fminf(ONE_EPS, mx + F_MARGIN);
        snb[tid] = mn - F_MARGIN;
    }
    __syncthreads();

    bf16x8 ifr[NG][4];
    int    li[NG];
    float  pb[NG], nb[NG];
    #pragma unroll
    for (int g = 0; g < NG; ++g) {
        int row = iw0 + g * 16 + c;
        #pragma unroll
        for (int ks = 0; ks < 4; ++ks)
            ifr[g][ks] = *(const bf16x8*)(fb + row * DDIM + ks * 32 + q * 8);
        li[g] = labels[row];
        pb[g] = spb[w * 64 + g * 16 + c];
        nb[g] = snb[w * 64 + g * 16 + c];
    }

    float ps[NG], ns[NG];
    #pragma unroll
    for (int g = 0; g < NG; ++g) { ps[g] = 0.f; ns[g] = 0.f; }

    const ushort* jptr = fb + (size_t)(j0 + c) * DDIM + q * 8;
    const int*    lptr = labels + j0 + q * 4;

    bf16x8 jfr[4];
    #pragma unroll
    for (int ks = 0; ks < 4; ++ks) jfr[ks] = *(const bf16x8*)(jptr + ks * 32);
    int4 lj = *(const int4*)lptr;

    #pragma unroll 1
    for (int jt = 0; jt < NJT; ++jt) {
        const int nj = (jt + 1) & (NJT - 1);
        const ushort* np = jptr + (size_t)nj * JT * DDIM;
        const int*    nl = lptr + nj * JT;

        f32x4 a0 = {0.f,0.f,0.f,0.f}, a1 = {0.f,0.f,0.f,0.f};
        #pragma unroll
        for (int ks = 0; ks < 4; ++ks) a0 = __builtin_amdgcn_mfma_f32_16x16x32_bf16(jfr[ks], ifr[0][ks], a0, 0, 0, 0);
        #pragma unroll
        for (int ks = 0; ks < 4; ++ks) a1 = __builtin_amdgcn_mfma_f32_16x16x32_bf16(jfr[ks], ifr[1][ks], a1, 0, 0, 0);
        const int4 ljc = lj;

        #pragma unroll
        for (int r = 0; r < 4; ++r) {
            int ljr = (r == 0) ? ljc.x : (r == 1) ? ljc.y : (r == 2) ? ljc.z : ljc.w;
            #pragma unroll
            for (int g = 0; g < 2; ++g) {
                float s = (g == 0) ? a0[r] : a1[r];
                bool same = (li[g] == ljr);
                float e = exp2f(fmaf(s, same ? KP2A : KN2A, same ? KP2B : KN2B));
                bool lt = s < (same ? pb[g] : nb[g]);
                ps[g] += (same && lt)   ? e : 0.0f;
                ns[g] += (!same && !lt) ? e : 0.0f;
            }
        }

        f32x4 a2 = {0.f,0.f,0.f,0.f}, a3 = {0.f,0.f,0.f,0.f};
        #pragma unroll
        for (int ks = 0; ks < 4; ++ks) a2 = __builtin_amdgcn_mfma_f32_16x16x32_bf16(jfr[ks], ifr[2][ks], a2, 0, 0, 0);
        #pragma unroll
        for (int ks = 0; ks < 4; ++ks) a3 = __builtin_amdgcn_mfma_f32_16x16x32_bf16(jfr[ks], ifr[3][ks], a3, 0, 0, 0);

        // prefetch next j-tile (jfr dead after the MFMAs above)
        #pragma unroll
        for (int ks = 0; ks < 4; ++ks) jfr[ks] = *(const bf16x8*)(np + ks * 32);
        lj = *(const int4*)nl;

        #pragma unroll
        for (int r = 0; r < 4; ++r) {
            int ljr = (r == 0) ? ljc.x : (r == 1) ? ljc.y : (r == 2) ? ljc.z : ljc.w;
            #pragma unroll
            for (int g = 2; g < 4; ++g) {
                float s = (g == 2) ? a2[r] : a3[r];
                bool same = (li[g] == ljr);
                float e = exp2f(fmaf(s, same ? KP2A : KN2A, same ? KP2B : KN2B));
                bool lt = s < (same ? pb[g] : nb[g]);
                ps[g] += (same && lt)   ? e : 0.0f;
                ns[g] += (!same && !lt) ? e : 0.0f;
            }
        }
    }

    #pragma unroll
    for (int g = 0; g < NG; ++g) {
        ps[g] += __shfl_xor(ps[g], 16, 64);
        ps[g] += __shfl_xor(ps[g], 32, 64);
        ns[g] += __shfl_xor(ns[g], 16, 64);
        ns[g] += __shfl_xor(ns[g], 32, 64);
    }
    if (q == 0) {
        #pragma unroll
        for (int g = 0; g < NG; ++g) {
            int row = iw0 + g * 16 + c;
            psum_part[blockIdx.y * B_N + row] = ps[g];
            nsum_part[blockIdx.y * B_N + row] = ns[g];
        }
    }
}

// ---------------------------------------------------------------- finalize
// validity: ps>0 && ns>0 == reference's valid (any kept pos term >= ~1e-27,
// any kept neg term >= ~1e-27 — never flush to 0; nonempty stage-2 masks
// imply has_pos/has_neg in the reference).
__global__ __launch_bounds__(256)
void ms_fin(const float* __restrict__ psum_part, const float* __restrict__ nsum_part,
            float* __restrict__ out)
{
    int i = blockIdx.x * 256 + threadIdx.x;
    float ps = 0.f, ns = 0.f;
    #pragma unroll
    for (int s = 0; s < JSPLIT; ++s) {
        ps += psum_part[s * B_N + i];
        ns += nsum_part[s * B_N + i];
    }
    float rl = 0.f;
    if (ps > 0.f && ns > 0.f)
        rl = log1pf(ps) * 0.5f + log1pf(ns) * 0.025f;   // /SCALE_POS, /SCALE_NEG

    #pragma unroll
    for (int off = 32; off > 0; off >>= 1) rl += __shfl_down(rl, off, 64);
    __shared__ float wsum[4];
    int lane = threadIdx.x & 63, wv = threadIdx.x >> 6;
    if (lane == 0) wsum[wv] = rl;
    __syncthreads();
    if (threadIdx.x == 0)
        atomicAdd(out, (wsum[0] + wsum[1] + wsum[2] + wsum[3]) * (1.0f / (float)B_N));
}

// ---------------------------------------------------------------- launch
extern "C" void kernel_launch(void* const* d_in, const int* in_sizes, int n_in,
                              void* d_out, int out_size, void* d_ws, size_t ws_size,
                              hipStream_t stream)
{
    const float* feats  = (const float*)d_in[0];
    const int*   labels = (const int*)d_in[1];

    char*   wsb       = (char*)d_ws;
    ushort* fb        = (ushort*)wsb;                          // 8192*128 bf16 = 2 MB
    float*  minp_part = (float*)(wsb + (size_t)2 * 1024 * 1024);
    float*  maxn_part = minp_part + (size_t)JSPLIT * B_N;      // 1 MB each
    float*  psum_part = maxn_part + (size_t)JSPLIT * B_N;
    float*  nsum_part = psum_part + (size_t)JSPLIT * B_N;

    hipMemsetAsync(d_out, 0, sizeof(float), stream);

    ms_cast<<<(B_N * DDIM) / (256 * 4), 256, 0, stream>>>(feats, fb);
    ms1<<<dim3(B_N / 256, JSPLIT), 256, 0, stream>>>(fb, labels, minp_part, maxn_part);
    ms2<<<dim3(B_N / 256, JSPLIT), 256, 0, stream>>>(fb, labels, minp_part, maxn_part,
                                                     psum_part, nsum_part);
    ms_fin<<<B_N / 256, 256, 0, stream>>>(psum_part, nsum_part, (float*)d_out);
}